// Round 1
// baseline (259.320 us; speedup 1.0000x reference)
//
#include <hip/hip_runtime.h>
#include <math.h>

#define N 4096

// ---------------------------------------------------------------------------
// Matvec: out[r] = act( sum_q W[r][q] * x[q] + b[r] )
// One wave (64 lanes) per row. 4 waves per 256-thread block -> 1024 blocks.
// mode 0: out = tanh(v)
// mode 1: out = v, out_sig = sigmoid(v)
// ---------------------------------------------------------------------------
__global__ __launch_bounds__(256) void mv_kernel(const float* __restrict__ W,
                                                 const float* __restrict__ b,
                                                 const float* __restrict__ x,
                                                 float* __restrict__ out,
                                                 float* __restrict__ out_sig,
                                                 int mode) {
    const int wave = threadIdx.x >> 6;
    const int lane = threadIdx.x & 63;
    const int row  = blockIdx.x * 4 + wave;

    const float4* Wr = reinterpret_cast<const float4*>(W + (size_t)row * N);
    const float4* xv = reinterpret_cast<const float4*>(x);

    float acc = 0.0f;
#pragma unroll
    for (int i = 0; i < 16; ++i) {
        float4 w4 = Wr[lane + i * 64];
        float4 x4 = xv[lane + i * 64];
        acc += w4.x * x4.x;
        acc += w4.y * x4.y;
        acc += w4.z * x4.z;
        acc += w4.w * x4.w;
    }

    // 64-lane butterfly reduce
#pragma unroll
    for (int off = 32; off > 0; off >>= 1)
        acc += __shfl_down(acc, off, 64);

    if (lane == 0) {
        float v = acc + b[row];
        if (mode == 0) {
            out[row] = tanhf(v);
        } else {
            out[row]     = v;
            out_sig[row] = 1.0f / (1.0f + expf(-v));
        }
    }
}

// ---------------------------------------------------------------------------
// Hebbian update: outW[p][q] = 2*A*(B*pre[q]*post[p] + C*pre[q] + D*post[p] + E)
// H layout: (p, q, 5) AoS. Each thread handles 4 consecutive q's:
// 20 floats = 5 float4 loads (16B-aligned since (p*4096+4t)*5*4 = 80*k bytes).
// ---------------------------------------------------------------------------
__global__ __launch_bounds__(256) void hebb_kernel(const float* __restrict__ H,
                                                   const float* __restrict__ pre,
                                                   const float* __restrict__ post,
                                                   float* __restrict__ outW) {
    const int idx = blockIdx.x * 256 + threadIdx.x; // one per 4 q's
    const int p   = idx >> 10;                      // 1024 groups of 4 per row
    const int q0  = (idx & 1023) << 2;

    const size_t base = ((size_t)p * N + q0) * 5;
    const float4* h4  = reinterpret_cast<const float4*>(H + base);
    float4 v0 = h4[0];
    float4 v1 = h4[1];
    float4 v2 = h4[2];
    float4 v3 = h4[3];
    float4 v4 = h4[4];

    const float f[20] = {v0.x, v0.y, v0.z, v0.w,
                         v1.x, v1.y, v1.z, v1.w,
                         v2.x, v2.y, v2.z, v2.w,
                         v3.x, v3.y, v3.z, v3.w,
                         v4.x, v4.y, v4.z, v4.w};

    const float  po = post[p];
    const float4 pr = *reinterpret_cast<const float4*>(pre + q0);
    const float  prs[4] = {pr.x, pr.y, pr.z, pr.w};

    float4 o;
    float* op = &o.x;
#pragma unroll
    for (int k = 0; k < 4; ++k) {
        const float A = f[5 * k + 0];
        const float B = f[5 * k + 1];
        const float C = f[5 * k + 2];
        const float D = f[5 * k + 3];
        const float E = f[5 * k + 4];
        op[k] = 2.0f * A * (B * prs[k] * po + C * prs[k] + D * po + E);
    }

    *reinterpret_cast<float4*>(outW + (size_t)p * N + q0) = o;
}

// ---------------------------------------------------------------------------
// Launch: MV0 -> Hebb0 -> MV1 -> Hebb1 -> MV2(+sigmoid) -> Hebb2
// d_in: x, W0, b0, H0, W1, b1, H1, W2, b2, H2
// d_out: y (4096) | new_W0 (16.7M) | new_W1 | new_W2   (all f32)
// ---------------------------------------------------------------------------
extern "C" void kernel_launch(void* const* d_in, const int* in_sizes, int n_in,
                              void* d_out, int out_size, void* d_ws, size_t ws_size,
                              hipStream_t stream) {
    const float* x  = (const float*)d_in[0];
    const float* W0 = (const float*)d_in[1];
    const float* b0 = (const float*)d_in[2];
    const float* H0 = (const float*)d_in[3];
    const float* W1 = (const float*)d_in[4];
    const float* b1 = (const float*)d_in[5];
    const float* H1 = (const float*)d_in[6];
    const float* W2 = (const float*)d_in[7];
    const float* b2 = (const float*)d_in[8];
    const float* H2 = (const float*)d_in[9];

    float* out = (float*)d_out;
    float* y   = out;                          // 4096
    float* oW0 = out + N;                      // 4096*4096
    float* oW1 = oW0 + (size_t)N * N;
    float* oW2 = oW1 + (size_t)N * N;

    float* s  = (float*)d_ws;
    float* s1 = s;          // tanh layer-0 output
    float* s2 = s + N;      // tanh layer-1 output
    float* s3 = s + 2 * N;  // sigmoid(y)

    const dim3 mvGrid(N / 4), mvBlock(256);
    const dim3 hGrid((size_t)N * N / 4 / 256), hBlock(256);

    hipLaunchKernelGGL(mv_kernel, mvGrid, mvBlock, 0, stream, W0, b0, x, s1, (float*)nullptr, 0);
    hipLaunchKernelGGL(hebb_kernel, hGrid, hBlock, 0, stream, H0, x, s1, oW0);

    hipLaunchKernelGGL(mv_kernel, mvGrid, mvBlock, 0, stream, W1, b1, s1, s2, (float*)nullptr, 0);
    hipLaunchKernelGGL(hebb_kernel, hGrid, hBlock, 0, stream, H1, s1, s2, oW1);

    hipLaunchKernelGGL(mv_kernel, mvGrid, mvBlock, 0, stream, W2, b2, s2, y, s3, 1);
    hipLaunchKernelGGL(hebb_kernel, hGrid, hBlock, 0, stream, H2, s2, s3, oW2);
}